// Round 3
// 342.415 us; speedup vs baseline: 1.0403x; 1.0403x over previous
//
#include <hip/hip_runtime.h>
#include <math.h>

#define LOG_CLAMP   (-100.0f)
#define NUM_CLASSES 80
#define BATCH       32
#define CONF_ITEMS  4    // cells per thread in conf path (R2-proven)

__device__ __forceinline__ float clogf_(float x) {
    return fmaxf(logf(x), LOG_CLAMP);
}
__device__ __forceinline__ float sigmoidf_(float z) {
    return 1.0f / (1.0f + expf(-z));
}

// Fused kernel A+B (harness-proven structure): blocks [0, conf_blocks) do the
// conf-column gather (256 threads x 4 cells); blocks [conf_blocks,
// conf_blocks+8) do per-target losses, one wave per batch (4 batches/block).
__global__ void __launch_bounds__(256)
fused_kernel(const float* __restrict__ pred,
             const float* __restrict__ tgt,
             const int* __restrict__ Hp,
             const int* __restrict__ Wp,
             int HW, int T, int n_cells, int conf_blocks, int full_conf_blocks,
             float* __restrict__ conf_part,
             float* __restrict__ part_xy,
             float* __restrict__ part_wh,
             float* __restrict__ part_cls,
             float* __restrict__ part_corr,
             float* __restrict__ part_nt) {
    __shared__ float sw[4];
    __shared__ int s_gi[4][64];
    __shared__ int s_val[4][64];

    if (blockIdx.x < (unsigned)conf_blocks) {
        // ---- conf path (identical math to proven R0 version) ----
        int cb   = (int)blockIdx.x;
        int base = cb * (blockDim.x * CONF_ITEMS) + threadIdx.x;
        float acc = 0.0f;
        if (cb < full_conf_blocks) {
            // whole block in range (n_cells = 800*1024 exactly): no per-cell
            // guard -> 4 loads issue back-to-back; nontemporal (no reuse).
#pragma unroll
            for (int k = 0; k < CONF_ITEMS; ++k) {
                int cell = base + k * 256;
                float z = __builtin_nontemporal_load(pred + (size_t)cell * 85 + 4);
                float p = sigmoidf_(z);
                acc += -clogf_(1.0f - p);
            }
        } else {
#pragma unroll
            for (int k = 0; k < CONF_ITEMS; ++k) {
                int cell = base + k * 256;
                if (cell < n_cells) {
                    float z = pred[(size_t)cell * 85 + 4];
                    float p = sigmoidf_(z);
                    acc += -clogf_(1.0f - p);
                }
            }
        }
        for (int off = 32; off > 0; off >>= 1) acc += __shfl_down(acc, off, 64);
        int lane = threadIdx.x & 63;
        int wave = threadIdx.x >> 6;
        if (lane == 0) sw[wave] = acc;
        __syncthreads();
        if (threadIdx.x == 0) {
            float s = sw[0] + sw[1] + sw[2] + sw[3];
            conf_part[blockIdx.x] = s;
        }
        return;
    }

    // ---- target path: one wave per batch ----
    int tb   = blockIdx.x - conf_blocks;     // 0..7
    int wave = threadIdx.x >> 6;             // 0..3
    int t    = threadIdx.x & 63;             // lane = target index
    int b    = tb * 4 + wave;                // batch 0..31
    int Wi = *Wp, Hi = *Hp;
    float Wf = (float)Wi, Hf = (float)Hi;

    float vxy = 0.f, vwh = 0.f, vcls = 0.f, vcorr = 0.f, vnt = 0.f;

    int my_gi = -1, my_valid = 0;
    float cx = 0.f, cy = 0.f, w = 0.f, h = 0.f;
    int cid = 0;

    if (t < T) {
        const float* tp = tgt + ((size_t)b * T + t) * 5;
        float f0 = tp[0], f1 = tp[1], f2 = tp[2], f3 = tp[3], f4 = tp[4];
        cid = (int)f0; cx = f1; cy = f2; w = f3; h = f4;
        float gx = floorf(cx * Wf);
        float gy = floorf(cy * Hf);
        bool finite = isfinite(f0) && isfinite(f1) && isfinite(f2) &&
                      isfinite(f3) && isfinite(f4);
        bool valid = finite && (gx >= 0.f) && (gx < Wf) && (gy >= 0.f) && (gy < Hf);
        float gxc = fminf(fmaxf(gx, 0.f), Wf - 1.f);
        float gyc = fminf(fmaxf(gy, 0.f), Hf - 1.f);
        my_gi = (int)gyc * Wi + (int)gxc;
        my_valid = valid ? 1 : 0;
    }
    s_gi[wave][t]  = my_gi;
    s_val[wave][t] = my_valid;
    __syncthreads();

    if (t < T && my_valid) {
        const float* pp = pred + ((size_t)b * HW + my_gi) * 85;
        float z0 = pp[0], z1 = pp[1], z2 = pp[2], z3 = pp[3];
        float gx = floorf(cx * Wf);
        float gy = floorf(cy * Hf);
        float tx = cx * Wf - gx;
        float ty = cy * Hf - gy;
        float dx = sigmoidf_(z0) - tx;
        float dy = sigmoidf_(z1) - ty;
        vxy = 0.5f * (dx * dx + dy * dy);
        float dw = expf(z2) - w * Wf;
        float dh = expf(z3) - h * Hf;
        vwh = 0.5f * (dw * dw + dh * dh);

        float csum = 0.f;
#pragma unroll 8
        for (int c = 0; c < NUM_CLASSES; ++c) {
            float p = sigmoidf_(pp[5 + c]);
            float l = (c == cid) ? clogf_(p) : clogf_(1.f - p);
            csum -= l;
        }
        vcls = csum * (1.0f / NUM_CLASSES);
        vnt = 1.0f;

        // conf correction only for the FIRST valid target hitting this cell
        // (matches .at[b,gi].max(vf) set-once semantics)
        bool first = true;
        for (int u = 0; u < t; ++u) {
            if (s_val[wave][u] && s_gi[wave][u] == my_gi) { first = false; break; }
        }
        if (first) {
            float pc = sigmoidf_(pp[4]);
            vcorr = clogf_(1.f - pc) - clogf_(pc);
        }
    }

    // per-wave (= per-batch) shuffle reduce of the 5 accumulators
    for (int off = 32; off > 0; off >>= 1) {
        vxy   += __shfl_down(vxy,   off, 64);
        vwh   += __shfl_down(vwh,   off, 64);
        vcls  += __shfl_down(vcls,  off, 64);
        vcorr += __shfl_down(vcorr, off, 64);
        vnt   += __shfl_down(vnt,   off, 64);
    }
    if (t == 0) {
        part_xy[b]   = vxy;
        part_wh[b]   = vwh;
        part_cls[b]  = vcls;
        part_corr[b] = vcorr;
        part_nt[b]   = vnt;
    }
}

// Kernel C: combine partials, write the 5 scalar outputs.
__global__ void final_kernel(const float* __restrict__ conf_part, int n_conf,
                             const float* __restrict__ part_xy,
                             const float* __restrict__ part_wh,
                             const float* __restrict__ part_cls,
                             const float* __restrict__ part_corr,
                             const float* __restrict__ part_nt,
                             int B, float n_cells_f,
                             float* __restrict__ out) {
    int tid = threadIdx.x;
    float c = 0.0f;
    for (int i = tid; i < n_conf; i += blockDim.x) c += conf_part[i];
    for (int off = 32; off > 0; off >>= 1) c += __shfl_down(c, off, 64);
    __shared__ float sw[4];
    if ((tid & 63) == 0) sw[tid >> 6] = c;
    __syncthreads();
    if (tid == 0) {
        float conf_base = sw[0] + sw[1] + sw[2] + sw[3];
        float sxy = 0.f, swh = 0.f, scls = 0.f, scorr = 0.f, snt = 0.f;
        for (int i = 0; i < B; ++i) {
            sxy   += part_xy[i];
            swh   += part_wh[i];
            scls  += part_cls[i];
            scorr += part_corr[i];
            snt   += part_nt[i];
        }
        float denom = fmaxf(snt, 1.0f);
        float lxy   = sxy  / denom;
        float lwh   = swh  / denom;
        float lcls  = scls / denom;
        float lconf = (conf_base + scorr) / n_cells_f;
        out[0] = lxy * 5.0f + lwh * 5.0f + lconf + lcls;
        out[1] = lxy;
        out[2] = lwh;
        out[3] = lconf;
        out[4] = lcls;
    }
}

extern "C" void kernel_launch(void* const* d_in, const int* in_sizes, int n_in,
                              void* d_out, int out_size, void* d_ws, size_t ws_size,
                              hipStream_t stream) {
    const float* pred = (const float*)d_in[0];
    const float* tgt  = (const float*)d_in[1];
    const int*   Hp   = (const int*)d_in[2];
    const int*   Wp   = (const int*)d_in[3];

    int n_pred  = in_sizes[0];              // B * HW * 85
    int n_cells = n_pred / 85;              // B * HW
    int B       = BATCH;                    // fixed by setup_inputs
    int HW      = n_cells / B;
    int T       = in_sizes[1] / (B * 5);    // 50

    const int conf_block = 256;
    const int cells_per_block = conf_block * CONF_ITEMS;          // 1024
    int full_conf_blocks = n_cells / cells_per_block;             // 800 (exact)
    int conf_blocks = (n_cells + cells_per_block - 1) / cells_per_block;
    int tgt_blocks  = (B + 3) / 4;          // 8: one wave per batch, 4 waves/block

    float* ws        = (float*)d_ws;
    float* conf_part = ws;                   // [conf_blocks]
    float* part_xy   = ws + conf_blocks;     // [B]
    float* part_wh   = part_xy + B;
    float* part_cls  = part_wh + B;
    float* part_corr = part_cls + B;
    float* part_nt   = part_corr + B;

    fused_kernel<<<conf_blocks + tgt_blocks, conf_block, 0, stream>>>(
        pred, tgt, Hp, Wp, HW, T, n_cells, conf_blocks, full_conf_blocks,
        conf_part, part_xy, part_wh, part_cls, part_corr, part_nt);
    final_kernel<<<1, 256, 0, stream>>>(conf_part, conf_blocks,
                                        part_xy, part_wh, part_cls, part_corr, part_nt,
                                        B, (float)n_cells, (float*)d_out);
}